// Round 2
// baseline (301.561 us; speedup 1.0000x reference)
//
#include <hip/hip_runtime.h>

#define NH 4
#define DK 16
#define HD 64
#define CQ 256
#define W 4096
#define BN 4

typedef unsigned short u16;
typedef __attribute__((ext_vector_type(8))) short bf16x8;
typedef __attribute__((ext_vector_type(4))) float f32x4;
typedef __attribute__((ext_vector_type(16))) float f32x16;
typedef __attribute__((ext_vector_type(4))) unsigned int u32x4;

__device__ inline u16 f2bf(float f) {
    unsigned int u = __float_as_uint(f);
    return (u16)((u + 0x7FFFu + ((u >> 16) & 1u)) >> 16);
}
__device__ inline float bf2f(u16 h) { return __uint_as_float(((unsigned)h) << 16); }

// ---------------------------------------------------------------------------
// Phase 1: 1x1-conv projections, LDS-tiled.
// grid = B(4) * wtile(64) * {q | kv}(2) = 512 blocks, 256 threads.
// Block stages x[256c][64w] (64KB LDS). Wave og == head h; each thread owns
// one w and the full 16-d row for its head -> 32B contiguous stores.
// q is pre-scaled by -log2(e) so the logits kernel needs no multiply.
// ---------------------------------------------------------------------------
__global__ __launch_bounds__(256, 2) void proj_kernel(
    const float* __restrict__ x_q, const float* __restrict__ x_kv,
    const float* __restrict__ wq, const float* __restrict__ bq,
    const float* __restrict__ wk, const float* __restrict__ bk,
    const float* __restrict__ wv, const float* __restrict__ bv,
    u16* __restrict__ qb, u16* __restrict__ kb, u16* __restrict__ vb)
{
    __shared__ float xs[CQ][64];
    const int id  = blockIdx.x;
    const int isq = id & 1;
    const int wt  = (id >> 1) & 63;
    const int b   = id >> 7;
    const int tid = threadIdx.x;
    const int w0  = wt * 64;

    const float* __restrict__ x = isq ? x_q : x_kv;
    {
        const int cw = tid >> 4;
        const int w4 = (tid & 15) * 4;
        #pragma unroll
        for (int it = 0; it < 16; ++it) {
            int c = it * 16 + cw;
            *(float4*)&xs[c][w4] =
                *(const float4*)(x + ((size_t)b * CQ + c) * W + w0 + w4);
        }
    }
    __syncthreads();

    const int w = tid & 63;
    const int h = __builtin_amdgcn_readfirstlane(tid >> 6);  // wave-uniform head
    const float QSCALE = -1.44269504088896340736f;

    if (isq) {
        float acc[DK];
        #pragma unroll
        for (int d = 0; d < DK; ++d) acc[d] = 0.f;
        #pragma unroll 4
        for (int c = 0; c < CQ; ++c) {
            float xv = xs[c][w];
            #pragma unroll
            for (int d = 0; d < DK; ++d)
                acc[d] += wq[(h * DK + d) * CQ + c] * xv;   // scalar s_load
        }
        u16 tmp[DK];
        #pragma unroll
        for (int d = 0; d < DK; ++d)
            tmp[d] = f2bf((acc[d] + bq[h * DK + d]) * QSCALE);
        u16* dst = qb + (((size_t)(b * NH + h)) * W + w0 + w) * DK;
        ((u32x4*)dst)[0] = ((u32x4*)tmp)[0];
        ((u32x4*)dst)[1] = ((u32x4*)tmp)[1];
    } else {
        float ak[DK], av[DK];
        #pragma unroll
        for (int d = 0; d < DK; ++d) { ak[d] = 0.f; av[d] = 0.f; }
        #pragma unroll 4
        for (int c = 0; c < CQ; ++c) {
            float xv = xs[c][w];
            #pragma unroll
            for (int d = 0; d < DK; ++d) {
                ak[d] += wk[(h * DK + d) * CQ + c] * xv;
                av[d] += wv[(h * DK + d) * CQ + c] * xv;
            }
        }
        u16 tk[DK], tv[DK];
        #pragma unroll
        for (int d = 0; d < DK; ++d) {
            tk[d] = f2bf(ak[d] + bk[h * DK + d]);
            tv[d] = f2bf(av[d] + bv[h * DK + d]);
        }
        size_t ro = (((size_t)(b * NH + h)) * W + w0 + w) * DK;
        ((u32x4*)(kb + ro))[0] = ((u32x4*)tk)[0];
        ((u32x4*)(kb + ro))[1] = ((u32x4*)tk)[1];
        ((u32x4*)(vb + ro))[0] = ((u32x4*)tv)[0];
        ((u32x4*)(vb + ro))[1] = ((u32x4*)tv)[1];
    }
}

// ---------------------------------------------------------------------------
// Phase 2: g[k] = sum_q sigmoid(q.k) via 32x32x16 bf16 MFMA (K = DK exactly),
// fused with S[bh][d] += sum_k g[k]*v[k][d] (shuffle-tree + atomics).
// One wave per (bh, ktile32, q-half): 16*128*2 = 4096 waves = 1024 blocks.
// q was pre-scaled by -log2(e): sigmoid = rcp(1 + exp2(logit)).
// ---------------------------------------------------------------------------
__global__ __launch_bounds__(256) void logits_kernel(
    const u16* __restrict__ qb, const u16* __restrict__ kb,
    const u16* __restrict__ vb, float* __restrict__ S)
{
    const int wid  = (blockIdx.x * 256 + (int)threadIdx.x) >> 6;
    const int lane = threadIdx.x & 63;
    const int qh   = wid & 1;
    const int kt   = (wid >> 1) & 127;
    const int bh   = wid >> 8;
    const int r    = lane & 31;
    const int d0   = (lane >> 5) * 8;

    const bf16x8 bfrag =
        *(const bf16x8*)(kb + (((size_t)bh * W + kt * 32 + r) * DK + d0));
    const u16* qp = qb + (((size_t)bh * W + qh * 2048 + r) * DK + d0);

    const f32x16 z = {0,0,0,0,0,0,0,0,0,0,0,0,0,0,0,0};
    float g0 = 0.f, g1 = 0.f, g2 = 0.f, g3 = 0.f;

    #pragma unroll 2
    for (int it = 0; it < 64; ++it) {
        bf16x8 a = *(const bf16x8*)(qp + (size_t)it * 32 * DK);
        f32x16 c = __builtin_amdgcn_mfma_f32_32x32x16_bf16(a, bfrag, z, 0, 0, 0);
        #pragma unroll
        for (int j = 0; j < 16; j += 4) {
            g0 += __builtin_amdgcn_rcpf(1.f + __builtin_amdgcn_exp2f(c[j + 0]));
            g1 += __builtin_amdgcn_rcpf(1.f + __builtin_amdgcn_exp2f(c[j + 1]));
            g2 += __builtin_amdgcn_rcpf(1.f + __builtin_amdgcn_exp2f(c[j + 2]));
            g3 += __builtin_amdgcn_rcpf(1.f + __builtin_amdgcn_exp2f(c[j + 3]));
        }
    }
    float g = (g0 + g1) + (g2 + g3);
    g += __shfl_xor(g, 32, 64);   // sum rows held by the other 32-lane group

    // fused: p[j] = g * v[k = kt*32+r][d0+j], reduce over the 32 k-lanes
    bf16x8 v8 = *(const bf16x8*)(vb + (((size_t)bh * W + kt * 32 + r) * DK + d0));
    float p[8];
    #pragma unroll
    for (int j = 0; j < 8; ++j) p[j] = g * bf2f((u16)v8[j]);
    #pragma unroll
    for (int m = 1; m < 32; m <<= 1) {
        #pragma unroll
        for (int j = 0; j < 8; ++j) p[j] += __shfl_xor(p[j], m, 64);
    }
    if (r == 0) {
        #pragma unroll
        for (int j = 0; j < 8; ++j)
            atomicAdd(&S[bh * DK + d0 + j], p[j]);
    }
}

// ---------------------------------------------------------------------------
// Phase 3: out[b][o] = bo[o] + sum_c wo[o][c] * S[b*64+c] / (Wq*Wkv)
// ---------------------------------------------------------------------------
__global__ __launch_bounds__(256) void out_kernel(
    const float* __restrict__ S, const float* __restrict__ wo,
    const float* __restrict__ bo, float* __restrict__ out)
{
    __shared__ float pooled[HD];
    const int b = blockIdx.x, t = threadIdx.x;
    if (t < HD) pooled[t] = S[b * HD + t] * (1.f / ((float)W * (float)W));
    __syncthreads();
    float val = bo[t];
    #pragma unroll
    for (int c2 = 0; c2 < HD; ++c2)
        val += wo[t * HD + c2] * pooled[c2];
    out[b * CQ + t] = val;
}

extern "C" void kernel_launch(void* const* d_in, const int* in_sizes, int n_in,
                              void* d_out, int out_size, void* d_ws, size_t ws_size,
                              hipStream_t stream) {
    const float* x_q  = (const float*)d_in[0];
    const float* x_kv = (const float*)d_in[1];
    const float* wq   = (const float*)d_in[2];
    const float* bq   = (const float*)d_in[3];
    const float* wk   = (const float*)d_in[4];
    const float* bk   = (const float*)d_in[5];
    const float* wv   = (const float*)d_in[6];
    const float* bv   = (const float*)d_in[7];
    const float* wo   = (const float*)d_in[8];
    const float* bo   = (const float*)d_in[9];
    float* out = (float*)d_out;

    char* ws = (char*)d_ws;
    u16*   qb = (u16*)ws;                    // 16*4096*16 bf16 = 2 MB
    u16*   kb = (u16*)(ws + (2u << 20));     // 2 MB
    u16*   vb = (u16*)(ws + (4u << 20));     // 2 MB
    float* S  = (float*)(ws + (6u << 20));   // 256 f32

    hipMemsetAsync(S, 0, BN * HD * sizeof(float), stream);
    proj_kernel<<<512, 256, 0, stream>>>(x_q, x_kv, wq, bq, wk, bk, wv, bv, qb, kb, vb);
    logits_kernel<<<1024, 256, 0, stream>>>(qb, kb, vb, S);
    out_kernel<<<BN, 256, 0, stream>>>(S, wo, bo, out);
}

// Round 3
// 97.287 us; speedup vs baseline: 3.0997x; 3.0997x over previous
//
#include <hip/hip_runtime.h>

#define NH 4
#define DK 16
#define HD 64
#define CQ 256
#define W 4096
#define BN 4

typedef unsigned short u16;
typedef unsigned int u32;
typedef __attribute__((ext_vector_type(8))) short bf16x8;
typedef __attribute__((ext_vector_type(4))) float f32x4;
typedef __attribute__((ext_vector_type(16))) float f32x16;

__device__ inline u32 pkbf(float a, float b) {
    u32 r;
    asm("v_cvt_pk_bf16_f32 %0, %1, %2" : "=v"(r) : "v"(a), "v"(b));
    return r;
}
__device__ inline bf16x8 pack8(const float* f) {
    union { u32 w[4]; bf16x8 v; } u;
    u.w[0] = pkbf(f[0], f[1]);
    u.w[1] = pkbf(f[2], f[3]);
    u.w[2] = pkbf(f[4], f[5]);
    u.w[3] = pkbf(f[6], f[7]);
    return u.v;
}
// split f32 into bf16 hi + bf16 lo (residual) fragments
__device__ inline void split8(const float* f, bf16x8* hi, bf16x8* lo) {
    union { u32 w[4]; bf16x8 v; } uh, ul;
    float r[8];
    #pragma unroll
    for (int i = 0; i < 8; i += 2) {
        u32 p = pkbf(f[i], f[i + 1]);
        uh.w[i >> 1] = p;
        r[i]     = f[i]     - __uint_as_float(p << 16);
        r[i + 1] = f[i + 1] - __uint_as_float(p & 0xffff0000u);
    }
    #pragma unroll
    for (int i = 0; i < 8; i += 2) ul.w[i >> 1] = pkbf(r[i], r[i + 1]);
    *hi = uh.v; *lo = ul.v;
}

#define MFMA(A, B, C) __builtin_amdgcn_mfma_f32_32x32x16_bf16((A), (B), (C), 0, 0, 0)
#define SIG(x) __builtin_amdgcn_rcpf(1.f + __builtin_amdgcn_exp2f(x))

// ---------------------------------------------------------------------------
// Phase 1: projections as per-wave 32x32x16 MFMA (M=out-ch, N=w, K=c).
// wave id -> (b, ot, wt, mat): mat 0 = q (1 MFMA), 1 = k+v (k: 1, v: 3 split-
// precision MFMAs, f32-quality). 2048 waves = 512 blocks.
// A-frag: lane&31 = o-row, (lane>>5)*8+j = c.  B-frag: lane&31 = w-col, same c.
// D: col=lane&31 (w), row=(j&3)+8*(j>>2)+4*(lane>>5) (o). q pre-scaled -log2e.
// ---------------------------------------------------------------------------
__global__ __launch_bounds__(256) void proj_kernel(
    const float* __restrict__ x_q, const float* __restrict__ x_kv,
    const float* __restrict__ wq, const float* __restrict__ bq,
    const float* __restrict__ wk, const float* __restrict__ bk,
    const float* __restrict__ wv, const float* __restrict__ bv,
    u16* __restrict__ qb, u16* __restrict__ kb, float* __restrict__ vbuf)
{
    const int wd   = blockIdx.x * 4 + ((int)threadIdx.x >> 6);
    const int lane = threadIdx.x & 63;
    const int mat  = wd & 1;
    const int wt   = (wd >> 1) & 127;
    const int ot   = (wd >> 8) & 1;
    const int b    = wd >> 9;

    const int n    = lane & 31;
    const int ks8  = (lane >> 5) * 8;
    const int o    = ot * 32 + n;
    const int wcol = wt * 32 + n;
    const float QS = -1.44269504088896340736f;

    const float* xp = (mat ? x_kv : x_q) + (size_t)b * CQ * W + wcol;

    const f32x16 z = {0,0,0,0,0,0,0,0,0,0,0,0,0,0,0,0};
    f32x16 acck = z, accv = z;

    if (mat == 0) {
        #pragma unroll 2
        for (int s = 0; s < 16; ++s) {
            const int c0 = s * 16 + ks8;
            float xf[8], wf[8];
            #pragma unroll
            for (int j = 0; j < 8; ++j) xf[j] = xp[(size_t)(c0 + j) * W];
            #pragma unroll
            for (int j = 0; j < 8; ++j) wf[j] = wq[o * CQ + c0 + j];
            acck = MFMA(pack8(wf), pack8(xf), acck);
        }
        #pragma unroll
        for (int j = 0; j < 16; j += 2) {
            int orow = ot * 32 + (j & 3) + 8 * (j >> 2) + 4 * (lane >> 5);
            float q0 = (acck[j] + bq[orow]) * QS;
            float q1 = (acck[j + 1] + bq[orow + 1]) * QS;
            int h = orow >> 4, d = orow & 15;
            *(u32*)(qb + ((size_t)(b * NH + h) * W + wcol) * DK + d) = pkbf(q0, q1);
        }
    } else {
        #pragma unroll 2
        for (int s = 0; s < 16; ++s) {
            const int c0 = s * 16 + ks8;
            float xf[8], kf[8], vf[8];
            #pragma unroll
            for (int j = 0; j < 8; ++j) xf[j] = xp[(size_t)(c0 + j) * W];
            #pragma unroll
            for (int j = 0; j < 8; ++j) kf[j] = wk[o * CQ + c0 + j];
            #pragma unroll
            for (int j = 0; j < 8; ++j) vf[j] = wv[o * CQ + c0 + j];
            bf16x8 xhi, xlo, whi, wlo;
            split8(xf, &xhi, &xlo);
            split8(vf, &whi, &wlo);
            acck = MFMA(pack8(kf), xhi, acck);
            accv = MFMA(whi, xhi, accv);
            accv = MFMA(whi, xlo, accv);
            accv = MFMA(wlo, xhi, accv);
        }
        #pragma unroll
        for (int j = 0; j < 16; j += 2) {
            int orow = ot * 32 + (j & 3) + 8 * (j >> 2) + 4 * (lane >> 5);
            int h = orow >> 4, d = orow & 15;
            size_t base = ((size_t)(b * NH + h) * W + wcol) * DK + d;
            *(u32*)(kb + base) = pkbf(acck[j] + bk[orow], acck[j + 1] + bk[orow + 1]);
            float2 vv = make_float2(accv[j] + bv[orow], accv[j + 1] + bv[orow + 1]);
            *(float2*)(vbuf + base) = vv;
        }
    }
}

// ---------------------------------------------------------------------------
// Phase 2: g[k] = sum_q sigmoid(q.k), fused with partial S = sum_k g[k]*v[k].
// Block (bh-uniform): 4 waves, wave handles 2 k-tiles (shared a-load, 2
// independent MFMA+sigmoid streams) x 512 q-rows. 2048 blocks, no atomics:
// per-block partial -> Spart[bh][grp][16].
// ---------------------------------------------------------------------------
__global__ __launch_bounds__(256) void logits_kernel(
    const u16* __restrict__ qb, const u16* __restrict__ kb,
    const float* __restrict__ vbuf, float* __restrict__ Spart)
{
    __shared__ float red[4][16];
    const int tid  = threadIdx.x;
    const int wv   = tid >> 6;
    const int lane = tid & 63;
    const int bh   = blockIdx.x >> 7;
    const int grp  = blockIdx.x & 127;   // (ktgroup 0..15) * 8 + (qs 0..7)
    const int ktg  = grp >> 3;
    const int qs   = grp & 7;
    const int kt0  = (ktg * 4 + wv) * 2;

    const int r  = lane & 31;
    const int d8 = (lane >> 5) * 8;

    const bf16x8 bf1 = *(const bf16x8*)(kb + (((size_t)bh * W + kt0 * 32 + r) * DK + d8));
    const bf16x8 bf2 = *(const bf16x8*)(kb + (((size_t)bh * W + (kt0 + 1) * 32 + r) * DK + d8));
    const u16* qp = qb + (((size_t)bh * W + qs * 512 + r) * DK + d8);

    const f32x16 z = {0,0,0,0,0,0,0,0,0,0,0,0,0,0,0,0};
    float a0=0.f,a1=0.f,a2=0.f,a3=0.f,b0=0.f,b1=0.f,b2=0.f,b3=0.f;

    bf16x8 aq = *(const bf16x8*)qp;
    #pragma unroll 4
    for (int it = 0; it < 16; ++it) {
        bf16x8 an = aq;
        if (it < 15) an = *(const bf16x8*)(qp + (size_t)(it + 1) * 32 * DK);
        f32x16 c1 = MFMA(aq, bf1, z);
        f32x16 c2 = MFMA(aq, bf2, z);
        #pragma unroll
        for (int j = 0; j < 16; j += 4) {
            a0 += SIG(c1[j]);     b0 += SIG(c2[j]);
            a1 += SIG(c1[j + 1]); b1 += SIG(c2[j + 1]);
            a2 += SIG(c1[j + 2]); b2 += SIG(c2[j + 2]);
            a3 += SIG(c1[j + 3]); b3 += SIG(c2[j + 3]);
        }
        aq = an;
    }
    float g1 = (a0 + a1) + (a2 + a3);
    float g2 = (b0 + b1) + (b2 + b3);
    g1 += __shfl_xor(g1, 32, 64);   // combine the two q-row halves (full g for k-col)
    g2 += __shfl_xor(g2, 32, 64);

    const float* vp1 = vbuf + (((size_t)bh * W + kt0 * 32 + r) * DK + d8);
    const float* vp2 = vbuf + (((size_t)bh * W + (kt0 + 1) * 32 + r) * DK + d8);
    f32x4 va = *(const f32x4*)vp1, vb4 = *(const f32x4*)(vp1 + 4);
    f32x4 vc = *(const f32x4*)vp2, vd4 = *(const f32x4*)(vp2 + 4);
    float p[8];
    #pragma unroll
    for (int j = 0; j < 4; ++j) {
        p[j]     = g1 * va[j]  + g2 * vc[j];
        p[4 + j] = g1 * vb4[j] + g2 * vd4[j];
    }
    #pragma unroll
    for (int m = 1; m < 32; m <<= 1) {
        #pragma unroll
        for (int j = 0; j < 8; ++j) p[j] += __shfl_xor(p[j], m, 64);
    }
    if (r == 0) {          // lanes 0 (d 0..7) and 32 (d 8..15)
        #pragma unroll
        for (int j = 0; j < 8; ++j) red[wv][d8 + j] = p[j];
    }
    __syncthreads();
    if (tid < 16) {
        float s = (red[0][tid] + red[1][tid]) + (red[2][tid] + red[3][tid]);
        Spart[((size_t)bh * 128 + grp) * 16 + tid] = s;
    }
}

// ---------------------------------------------------------------------------
// Phase 3: reduce Spart, scale, output conv.
// ---------------------------------------------------------------------------
__global__ __launch_bounds__(256) void out_kernel(
    const float* __restrict__ Spart, const float* __restrict__ wo,
    const float* __restrict__ bo, float* __restrict__ out)
{
    __shared__ float pooled[HD];
    const int b = blockIdx.x, t = threadIdx.x;
    if (t < HD) {
        int h = t >> 4, d = t & 15;
        const float* sp = Spart + ((size_t)(b * NH + h) * 128) * 16 + d;
        float s = 0.f;
        #pragma unroll 4
        for (int i = 0; i < 128; ++i) s += sp[i * 16];
        pooled[t] = s * (1.f / ((float)W * (float)W));
    }
    __syncthreads();
    float val = bo[t];
    #pragma unroll
    for (int c2 = 0; c2 < HD; ++c2)
        val += wo[t * HD + c2] * pooled[c2];
    out[b * CQ + t] = val;
}

extern "C" void kernel_launch(void* const* d_in, const int* in_sizes, int n_in,
                              void* d_out, int out_size, void* d_ws, size_t ws_size,
                              hipStream_t stream) {
    const float* x_q  = (const float*)d_in[0];
    const float* x_kv = (const float*)d_in[1];
    const float* wq   = (const float*)d_in[2];
    const float* bq   = (const float*)d_in[3];
    const float* wk   = (const float*)d_in[4];
    const float* bk   = (const float*)d_in[5];
    const float* wv   = (const float*)d_in[6];
    const float* bv   = (const float*)d_in[7];
    const float* wo   = (const float*)d_in[8];
    const float* bo   = (const float*)d_in[9];
    float* out = (float*)d_out;

    char* ws = (char*)d_ws;
    u16*   qb    = (u16*)ws;                    // 2 MB
    u16*   kb    = (u16*)(ws + (2u << 20));     // 2 MB
    float* vbuf  = (float*)(ws + (4u << 20));   // 4 MB (f32 V)
    float* Spart = (float*)(ws + (8u << 20));   // 16*128*16 f32 = 128 KB

    proj_kernel<<<512, 256, 0, stream>>>(x_q, x_kv, wq, bq, wk, bk, wv, bv, qb, kb, vbuf);
    logits_kernel<<<2048, 256, 0, stream>>>(qb, kb, vbuf, Spart);
    out_kernel<<<BN, 256, 0, stream>>>(Spart, wo, bo, out);
}